// Round 5
// baseline (1497.721 us; speedup 1.0000x reference)
//
#include <hip/hip_runtime.h>
#include <hip/hip_bf16.h>
#include <math.h>

#define EE 512      // E
#define HH 1024     // H
#define VV 50257    // V
#define KVN 1000    // KV
#define BB 64       // B
#define LL 512      // L
#define FH 4096     // 4H
#define TWOH 2048   // 2H

typedef __hip_bfloat16 bf16;
typedef short bf16x8 __attribute__((ext_vector_type(8)));
typedef float f32x4  __attribute__((ext_vector_type(4)));

__device__ __forceinline__ float sigm(float x){ return 1.0f/(1.0f+__expf(-x)); }

// RNE fp32 -> bf16 bits
__device__ __forceinline__ unsigned short f2bf(float f){
  unsigned int u = __float_as_uint(f);
  unsigned int r = (u + 0x7FFFu + ((u >> 16) & 1u)) >> 16;
  return (unsigned short)r;
}

// ---------------- gates init: gates[b][j] = b_ih[j] + b_hh[j] ----------------
__global__ __launch_bounds__(256)
void k_gates_init(const float* __restrict__ b_ih, const float* __restrict__ b_hh,
                  float* __restrict__ gates){
  int i = blockIdx.x*256 + threadIdx.x;
  int j = i & (FH-1);
  gates[i] = b_ih[j] + b_hh[j];
}

// ---------------- embed+gates GEMM (K-split 24, atomics into biased gates) ----------------
__global__ __launch_bounds__(256)
void k_embed_gates(const int* __restrict__ ids, const float* __restrict__ h,
                   const float* __restrict__ emb,
                   const float* __restrict__ W_ih, const float* __restrict__ W_hh,
                   float* __restrict__ gates){
  __shared__ float Xs[64][68];
  __shared__ float Ws[64][68];
  const int tid = threadIdx.x;
  const int nbase = blockIdx.x*64;
  const int kbase = blockIdx.y*64;
  {
    int b = tid >> 2;
    int kof = (tid & 3)*16;
    int id = ids[b];
    #pragma unroll
    for (int i=0;i<16;i++){
      int kg = kbase + kof + i;
      float v = (kg < EE) ? emb[(size_t)id*EE + kg] : h[(size_t)b*HH + (kg-EE)];
      Xs[kof+i][b] = v;
    }
  }
  {
    int n = tid & 63;
    int kr0 = tid >> 6;
    #pragma unroll
    for (int i=0;i<16;i++){
      int kr = kr0 + i*4;
      int kg = kbase + kr;
      float v = (kg < EE) ? W_ih[(size_t)kg*FH + nbase + n]
                          : W_hh[(size_t)(kg-EE)*FH + nbase + n];
      Ws[kr][n] = v;
    }
  }
  __syncthreads();
  const int tx = tid & 15, ty = tid >> 4;
  float acc[4][4] = {};
  for (int k=0;k<64;k++){
    float4 a4 = *(const float4*)(&Xs[k][ty*4]);
    float4 w4 = *(const float4*)(&Ws[k][tx*4]);
    float aa[4] = {a4.x,a4.y,a4.z,a4.w};
    float ww[4] = {w4.x,w4.y,w4.z,w4.w};
    #pragma unroll
    for (int i=0;i<4;i++)
      #pragma unroll
      for (int j=0;j<4;j++)
        acc[i][j] += aa[i]*ww[j];
  }
  #pragma unroll
  for (int i=0;i<4;i++){
    int b = ty*4 + i;
    #pragma unroll
    for (int j=0;j<4;j++)
      atomicAdd(&gates[(size_t)b*FH + nbase + tx*4 + j], acc[i][j]);
  }
}

// ---------------- LSTM cell + bf16 hcat first half ----------------
__global__ __launch_bounds__(256)
void k_lstm(const float* __restrict__ gates, const float* __restrict__ c_in,
            float* __restrict__ hout, float* __restrict__ cout,
            bf16* __restrict__ hcatb){
  int idx = blockIdx.x*256 + threadIdx.x;
  int b = idx >> 10, hh = idx & 1023;
  const float* g = gates + (size_t)b*FH;
  float ig = g[hh], fg = g[HH+hh], gg = g[2*HH+hh], og = g[3*HH+hh];
  float ct = sigm(fg)*c_in[idx] + sigm(ig)*tanhf(gg);
  float ht = sigm(og)*tanhf(ct);
  hout[idx] = ht;
  cout[idx] = ct;
  hcatb[(size_t)b*TWOH + hh] = __float2bfloat16(ht);
}

// ---------------- q1/p1 rank-collapsed precomputes ----------------
__global__ __launch_bounds__(256)
void k_q1p1(const float* __restrict__ ht, const float* __restrict__ ctx,
            const float* __restrict__ aW1, const float* __restrict__ ab1,
            const float* __restrict__ kW1, const float* __restrict__ kb1,
            float* __restrict__ q1, float* __restrict__ p1){
  int e = blockIdx.x*256 + threadIdx.x;
  int b = blockIdx.y;
  float aq = 0.f, ap = 0.f;
  for (int k2 = 0; k2 < HH; ++k2){
    float hv = ht[(size_t)b*HH + k2];
    float cv = ctx[(size_t)b*HH + k2];
    aq += hv * aW1[(size_t)(HH+k2)*EE + e];
    ap += cv * kW1[(size_t)k2*EE + e];
    ap += hv * kW1[(size_t)(HH+k2)*EE + e];
  }
  q1[(size_t)b*EE + e] = aq + ab1[e];
  p1[(size_t)b*EE + e] = ap + kb1[e];
}

// ---------------- p2[kv,e] = k[kv] @ kW1[2H:,:] ----------------
__global__ __launch_bounds__(256)
void k_p2(const float* __restrict__ kin, const float* __restrict__ kW1,
          float* __restrict__ p2){
  int e  = blockIdx.x*256 + threadIdx.x;
  int kv = blockIdx.y;
  float a = 0.f;
  for (int k2 = 0; k2 < EE; ++k2)
    a += kin[(size_t)kv*EE + k2] * kW1[(size_t)(TWOH+k2)*EE + e];
  p2[(size_t)kv*EE + e] = a;
}

// ---------------- transpose+convert: Wt[n][k] = bf16(W[k][n]) ----------------
__global__ __launch_bounds__(256)
void k_transpose_bf16(const float* __restrict__ W, bf16* __restrict__ Wt,
                      int K, int N){
  __shared__ float t[32][33];
  int k0 = blockIdx.y*32, n0 = blockIdx.x*32;
  int tx = threadIdx.x & 31, ty = threadIdx.x >> 5;
  #pragma unroll
  for (int i=0;i<4;i++){
    int kk = ty + i*8;
    t[kk][tx] = W[(size_t)(k0+kk)*N + n0 + tx];
  }
  __syncthreads();
  #pragma unroll
  for (int i=0;i<4;i++){
    int nn = ty + i*8;
    Wt[(size_t)(n0+nn)*K + k0 + tx] = __float2bfloat16(t[tx][nn]);
  }
}

// =====================================================================
// Shared BN=512 full-row MFMA core pieces: BM=32, block 256 (4 waves, each
// covering n-slice wid*128). K-chunk BK=32. acc 2 m-frags x 8 n-frags.
// Bs layout [n][k] stride 40; As [m][k] stride 40.
// =====================================================================

// --- a2 path: A = U1 bf16 [32768,512]; out ulog[m] = ab3 + sum_n tanh(.+ab2[n])*aW3[n]
__global__ __launch_bounds__(256)
void k_mfma_tanh_dot(const bf16* __restrict__ A, const bf16* __restrict__ Wt,
                     const float* __restrict__ bias, const float* __restrict__ w3,
                     const float* __restrict__ b3, float* __restrict__ logits){
  __shared__ short As[32*40];
  __shared__ short Bs[512*40];
  __shared__ float red[4][32];
  const int tid  = threadIdx.x;
  const int lane = tid & 63, wid = tid >> 6;
  const int quad = lane >> 4, l16 = lane & 15;
  const int m0 = blockIdx.x*32;

  f32x4 acc[2][8] = {};
  for (int k0 = 0; k0 < 512; k0 += 32){
    if (tid < 128){
      int row = tid >> 2, cg = tid & 3;
      *(bf16x8*)(As + row*40 + cg*8) =
        *(const bf16x8*)((const short*)A + (size_t)(m0+row)*512 + k0 + cg*8);
    }
    #pragma unroll
    for (int it = 0; it < 8; ++it){
      int grp = tid + it*256;            // 2048 groups
      int row = grp >> 2, cg = grp & 3;
      *(bf16x8*)(Bs + row*40 + cg*8) =
        *(const bf16x8*)((const short*)Wt + (size_t)row*512 + k0 + cg*8);
    }
    __syncthreads();
    bf16x8 af[2], bfr[8];
    #pragma unroll
    for (int mt=0; mt<2; ++mt)
      af[mt] = *(const bf16x8*)(As + (mt*16 + l16)*40 + quad*8);
    #pragma unroll
    for (int nt=0; nt<8; ++nt)
      bfr[nt] = *(const bf16x8*)(Bs + (wid*128 + nt*16 + l16)*40 + quad*8);
    #pragma unroll
    for (int mt=0; mt<2; ++mt)
      #pragma unroll
      for (int nt=0; nt<8; ++nt)
        acc[mt][nt] = __builtin_amdgcn_mfma_f32_16x16x32_bf16(af[mt], bfr[nt], acc[mt][nt], 0, 0, 0);
    __syncthreads();
  }
  float bv[8], wv[8];
  #pragma unroll
  for (int nt=0; nt<8; ++nt){
    int n = wid*128 + nt*16 + l16;
    bv[nt] = bias[n]; wv[nt] = w3[n];
  }
  #pragma unroll
  for (int mt=0; mt<2; ++mt){
    #pragma unroll
    for (int r=0; r<4; ++r){
      float s = 0.f;
      #pragma unroll
      for (int nt=0; nt<8; ++nt)
        s += tanhf(acc[mt][nt][r] + bv[nt]) * wv[nt];
      #pragma unroll
      for (int off=8; off>=1; off>>=1) s += __shfl_xor(s, off, 16);
      if (l16 == 0) red[wid][mt*16 + quad*4 + r] = s;
    }
  }
  __syncthreads();
  if (tid < 32){
    float s = red[0][tid] + red[1][tid] + red[2][tid] + red[3][tid];
    logits[m0 + tid] = s + b3[0];
  }
}

// --- key path: A staged as tanh(p1[b]+p2[kv]) on the fly
__global__ __launch_bounds__(256)
void k_mfma_key(const float* __restrict__ p1, const float* __restrict__ p2,
                const bf16* __restrict__ Wt,
                const float* __restrict__ bias, const float* __restrict__ w3,
                const float* __restrict__ b3, float* __restrict__ logits){
  __shared__ short As[32*40];
  __shared__ short Bs[512*40];
  __shared__ float red[4][32];
  const int tid  = threadIdx.x;
  const int lane = tid & 63, wid = tid >> 6;
  const int quad = lane >> 4, l16 = lane & 15;
  const int m0 = blockIdx.x*32;

  f32x4 acc[2][8] = {};
  for (int k0 = 0; k0 < 512; k0 += 32){
    {
      int row = tid >> 3, g = tid & 7;   // 32 rows x 8 groups of 4
      int m = m0 + row;
      int b = m / KVN;
      int kv = m - b*KVN;
      int e = k0 + g*4;
      float4 a0 = *(const float4*)(p1 + (size_t)b*EE + e);
      float4 c0 = *(const float4*)(p2 + (size_t)kv*EE + e);
      uint2 pk;
      pk.x = (unsigned int)f2bf(tanhf(a0.x+c0.x)) | ((unsigned int)f2bf(tanhf(a0.y+c0.y)) << 16);
      pk.y = (unsigned int)f2bf(tanhf(a0.z+c0.z)) | ((unsigned int)f2bf(tanhf(a0.w+c0.w)) << 16);
      *(uint2*)(As + row*40 + g*4) = pk;
    }
    #pragma unroll
    for (int it = 0; it < 8; ++it){
      int grp = tid + it*256;
      int row = grp >> 2, cg = grp & 3;
      *(bf16x8*)(Bs + row*40 + cg*8) =
        *(const bf16x8*)((const short*)Wt + (size_t)row*512 + k0 + cg*8);
    }
    __syncthreads();
    bf16x8 af[2], bfr[8];
    #pragma unroll
    for (int mt=0; mt<2; ++mt)
      af[mt] = *(const bf16x8*)(As + (mt*16 + l16)*40 + quad*8);
    #pragma unroll
    for (int nt=0; nt<8; ++nt)
      bfr[nt] = *(const bf16x8*)(Bs + (wid*128 + nt*16 + l16)*40 + quad*8);
    #pragma unroll
    for (int mt=0; mt<2; ++mt)
      #pragma unroll
      for (int nt=0; nt<8; ++nt)
        acc[mt][nt] = __builtin_amdgcn_mfma_f32_16x16x32_bf16(af[mt], bfr[nt], acc[mt][nt], 0, 0, 0);
    __syncthreads();
  }
  float bv[8], wv[8];
  #pragma unroll
  for (int nt=0; nt<8; ++nt){
    int n = wid*128 + nt*16 + l16;
    bv[nt] = bias[n]; wv[nt] = w3[n];
  }
  #pragma unroll
  for (int mt=0; mt<2; ++mt){
    #pragma unroll
    for (int r=0; r<4; ++r){
      float s = 0.f;
      #pragma unroll
      for (int nt=0; nt<8; ++nt)
        s += tanhf(acc[mt][nt][r] + bv[nt]) * wv[nt];
      #pragma unroll
      for (int off=8; off>=1; off>>=1) s += __shfl_xor(s, off, 16);
      if (l16 == 0) red[wid][mt*16 + quad*4 + r] = s;
    }
  }
  __syncthreads();
  if (tid < 32){
    float s = red[0][tid] + red[1][tid] + red[2][tid] + red[3][tid];
    logits[m0 + tid] = s + b3[0];
  }
}

// --- a1 path: A = enc fp32 [32768,1024] converted on the fly; K=1024.
//     out U1[m][n] = bf16(tanh(C + q1[b][n]))
__global__ __launch_bounds__(256)
void k_mfma_a1(const float* __restrict__ enc, const bf16* __restrict__ Wt,
               const float* __restrict__ q1, bf16* __restrict__ U1){
  __shared__ short As[32*40];
  __shared__ short Bs[512*40];
  const int tid  = threadIdx.x;
  const int lane = tid & 63, wid = tid >> 6;
  const int quad = lane >> 4, l16 = lane & 15;
  const int m0 = blockIdx.x*32;

  f32x4 acc[2][8] = {};
  for (int k0 = 0; k0 < 1024; k0 += 32){
    {
      int row = tid >> 3, g = tid & 7;
      float4 f = *(const float4*)(enc + (size_t)(m0+row)*1024 + k0 + g*4);
      uint2 pk;
      pk.x = (unsigned int)f2bf(f.x) | ((unsigned int)f2bf(f.y) << 16);
      pk.y = (unsigned int)f2bf(f.z) | ((unsigned int)f2bf(f.w) << 16);
      *(uint2*)(As + row*40 + g*4) = pk;
    }
    #pragma unroll
    for (int it = 0; it < 8; ++it){
      int grp = tid + it*256;
      int row = grp >> 2, cg = grp & 3;
      *(bf16x8*)(Bs + row*40 + cg*8) =
        *(const bf16x8*)((const short*)Wt + (size_t)row*1024 + k0 + cg*8);
    }
    __syncthreads();
    bf16x8 af[2], bfr[8];
    #pragma unroll
    for (int mt=0; mt<2; ++mt)
      af[mt] = *(const bf16x8*)(As + (mt*16 + l16)*40 + quad*8);
    #pragma unroll
    for (int nt=0; nt<8; ++nt)
      bfr[nt] = *(const bf16x8*)(Bs + (wid*128 + nt*16 + l16)*40 + quad*8);
    #pragma unroll
    for (int mt=0; mt<2; ++mt)
      #pragma unroll
      for (int nt=0; nt<8; ++nt)
        acc[mt][nt] = __builtin_amdgcn_mfma_f32_16x16x32_bf16(af[mt], bfr[nt], acc[mt][nt], 0, 0, 0);
    __syncthreads();
  }
  const int b = m0 >> 9;
  const float* q1r = q1 + (size_t)b*EE;
  #pragma unroll
  for (int mt=0; mt<2; ++mt){
    #pragma unroll
    for (int r=0; r<4; ++r){
      int m = m0 + mt*16 + quad*4 + r;
      #pragma unroll
      for (int nt=0; nt<8; ++nt){
        int n = wid*128 + nt*16 + l16;
        U1[(size_t)m*EE + n] = __float2bfloat16(tanhf(acc[mt][nt][r] + q1r[n]));
      }
    }
  }
}

// ---------------- hctx: inline softmax over ulog row, weighted enc sum, bf16 out ----------------
// grid (4, 64), block 256
__global__ __launch_bounds__(256)
void k_hctx(const float* __restrict__ ulog, const float* __restrict__ enc,
            bf16* __restrict__ hcatb){
  __shared__ float wts[512];
  __shared__ float red[256];
  int b = blockIdx.y, tid = threadIdx.x;
  const float* row = ulog + (size_t)b*LL;
  float u0 = row[tid], u1 = row[tid+256];
  red[tid] = fmaxf(u0, u1);
  __syncthreads();
  for (int s=128;s>0;s>>=1){ if (tid<s) red[tid]=fmaxf(red[tid],red[tid+s]); __syncthreads(); }
  float mx = red[0];
  __syncthreads();
  float e0 = __expf(u0-mx), e1 = __expf(u1-mx);
  red[tid] = e0+e1;
  __syncthreads();
  for (int s=128;s>0;s>>=1){ if (tid<s) red[tid]+=red[tid+s]; __syncthreads(); }
  float inv = 1.f/red[0];
  wts[tid] = e0*inv; wts[tid+256] = e1*inv;
  __syncthreads();
  int hh = blockIdx.x*256 + tid;
  float s = 0.f;
  for (int l=0;l<LL;l++)
    s += wts[l] * enc[((size_t)b*LL + l)*HH + hh];
  hcatb[(size_t)b*TWOH + HH + hh] = __float2bfloat16(s);
}

// =====================================================================
// Final projection: y[b][v] = hcatb[b]@alW[:,v] + alb[v] + uk.  Full K=2048,
// BN=64, no atomics. grid 786, block 256 (4 waves x 16n each).
// =====================================================================
__global__ __launch_bounds__(256)
void k_final_mfma(const bf16* __restrict__ hcatb, const float* __restrict__ alW,
                  const float* __restrict__ alb, const float* __restrict__ uklog,
                  float* __restrict__ y){
  __shared__ short As[64*40];        // [m][k] bf16
  __shared__ short Bs[64*40];        // [n][k] bf16 (converted from fp32)
  const int tid  = threadIdx.x;
  const int lane = tid & 63, wid = tid >> 6;
  const int quad = lane >> 4, l16 = lane & 15;
  const int n0 = blockIdx.x*64;

  f32x4 acc[4] = {};
  const int nst = tid & 63;          // staging col
  const int kst = (tid >> 6)*8;      // staging k-group base
  const int vst = n0 + nst;
  const bool okst = vst < VV;
  for (int k0 = 0; k0 < TWOH; k0 += 32){
    {
      int rowm = tid >> 2, cg = tid & 3;
      *(bf16x8*)(As + rowm*40 + cg*8) =
        *(const bf16x8*)((const short*)hcatb + (size_t)rowm*TWOH + k0 + cg*8);
    }
    {
      // B: 64 n x 32 k fp32 -> bf16. thread covers col nst, k rows kst..kst+7
      #pragma unroll
      for (int j=0;j<8;j++){
        int kk = kst + j;
        float v = okst ? alW[(size_t)(k0+kk)*VV + vst] : 0.f;
        Bs[nst*40 + kk] = (short)f2bf(v);
      }
    }
    __syncthreads();
    bf16x8 bfr = *(const bf16x8*)(Bs + (wid*16 + l16)*40 + quad*8);
    #pragma unroll
    for (int mt=0; mt<4; ++mt){
      bf16x8 af = *(const bf16x8*)(As + (mt*16 + l16)*40 + quad*8);
      acc[mt] = __builtin_amdgcn_mfma_f32_16x16x32_bf16(af, bfr, acc[mt], 0, 0, 0);
    }
    __syncthreads();
  }
  int v = n0 + wid*16 + l16;
  if (v < VV){
    float bias = alb[v];
    int dk = v - (VV - KVN);
    #pragma unroll
    for (int mt=0; mt<4; ++mt){
      #pragma unroll
      for (int r=0; r<4; ++r){
        int b = mt*16 + quad*4 + r;
        float o = acc[mt][r] + bias;
        if (dk >= 0) o += uklog[b*KVN + dk];
        y[(size_t)b*VV + v] = o;
      }
    }
  }
}

// ---------------- parallel log-sum-exp partials ----------------
#define LSE_CH 6283
__global__ __launch_bounds__(256)
void k_lse_part(const float* __restrict__ y, float* __restrict__ pmax,
                float* __restrict__ psum){
  __shared__ float sm[256], ss[256];
  int b = blockIdx.y, chunk = blockIdx.x, tid = threadIdx.x;
  int start = chunk*LSE_CH;
  int end = start + LSE_CH; if (end > VV) end = VV;
  const float* row = y + (size_t)b*VV;
  float m = -1e30f, s = 0.f;
  for (int i = start + tid; i < end; i += 256){
    float v = row[i];
    if (v > m){ s = s*__expf(m - v) + 1.f; m = v; }
    else s += __expf(v - m);
  }
  sm[tid] = m; ss[tid] = s;
  __syncthreads();
  for (int st=128; st>0; st>>=1){
    if (tid < st){
      float m2 = sm[tid+st], s2 = ss[tid+st];
      float M = fmaxf(sm[tid], m2);
      ss[tid] = ss[tid]*__expf(sm[tid]-M) + s2*__expf(m2-M);
      sm[tid] = M;
    }
    __syncthreads();
  }
  if (tid == 0){ pmax[b*8 + chunk] = sm[0]; psum[b*8 + chunk] = ss[0]; }
}

// ---------------- apply: y -= lse (combine inline) ----------------
__global__ __launch_bounds__(256)
void k_lse_apply(float* __restrict__ y, const float* __restrict__ pmax,
                 const float* __restrict__ psum){
  int idx = blockIdx.x*256 + threadIdx.x;
  if (idx >= BB*VV) return;
  int b = idx / VV;
  float m = -1e30f;
  #pragma unroll
  for (int i=0;i<8;i++) m = fmaxf(m, pmax[b*8+i]);
  float s = 0.f;
  #pragma unroll
  for (int i=0;i<8;i++) s += psum[b*8+i]*__expf(pmax[b*8+i]-m);
  y[idx] -= m + logf(s);
}

extern "C" void kernel_launch(void* const* d_in, const int* in_sizes, int n_in,
                              void* d_out, int out_size, void* d_ws, size_t ws_size,
                              hipStream_t stream) {
  const int*   ids  = (const int*)  d_in[0];
  const float* h    = (const float*)d_in[1];
  const float* c    = (const float*)d_in[2];
  const float* kin  = (const float*)d_in[3];
  const float* ctx  = (const float*)d_in[4];
  const float* enc  = (const float*)d_in[5];
  const float* emb  = (const float*)d_in[6];
  const float* W_ih = (const float*)d_in[7];
  const float* W_hh = (const float*)d_in[8];
  const float* b_ih = (const float*)d_in[9];
  const float* b_hh = (const float*)d_in[10];
  const float* aW1  = (const float*)d_in[11];
  const float* ab1  = (const float*)d_in[12];
  const float* aW2  = (const float*)d_in[13];
  const float* ab2  = (const float*)d_in[14];
  const float* aW3  = (const float*)d_in[15];
  const float* ab3  = (const float*)d_in[16];
  const float* kW1  = (const float*)d_in[17];
  const float* kb1  = (const float*)d_in[18];
  const float* kW2  = (const float*)d_in[19];
  const float* kb2  = (const float*)d_in[20];
  const float* kW3  = (const float*)d_in[21];
  const float* kb3  = (const float*)d_in[22];
  const float* alW  = (const float*)d_in[23];
  const float* alb  = (const float*)d_in[24];

  float* y      = (float*)d_out;
  float* ht_out = y + (size_t)BB*VV;
  float* ct_out = ht_out + (size_t)BB*HH;

  char* w = (char*)d_ws;
  float* gates = (float*)w;  w += (size_t)BB*FH*4;        // 1 MB
  float* q1    = (float*)w;  w += (size_t)BB*EE*4;
  float* p1    = (float*)w;  w += (size_t)BB*EE*4;
  float* p2    = (float*)w;  w += (size_t)KVN*EE*4;       // 2 MB
  float* ulog  = (float*)w;  w += (size_t)BB*LL*4;
  float* uklog = (float*)w;  w += (size_t)BB*KVN*4;
  bf16*  hcatb = (bf16*)w;   w += (size_t)BB*TWOH*2;      // 256 KB
  bf16*  U1    = (bf16*)w;   w += (size_t)BB*LL*EE*2;     // 33.5 MB
  bf16*  aW1t  = (bf16*)w;   w += (size_t)EE*HH*2;        // 1 MB
  bf16*  aW2t  = (bf16*)w;   w += (size_t)EE*EE*2;        // 0.5 MB
  bf16*  kW2t  = (bf16*)w;   w += (size_t)EE*EE*2;        // 0.5 MB
  float* pmax  = (float*)w;  w += (size_t)BB*8*4;
  float* psum  = (float*)w;  w += (size_t)BB*8*4;

  const int NBLK = (BB*VV + 255)/256;

  // 0. weight transposes -> bf16
  k_transpose_bf16<<<dim3(EE/32, HH/32), 256, 0, stream>>>(aW1, aW1t, HH, EE);
  k_transpose_bf16<<<dim3(EE/32, EE/32), 256, 0, stream>>>(aW2, aW2t, EE, EE);
  k_transpose_bf16<<<dim3(EE/32, EE/32), 256, 0, stream>>>(kW2, kW2t, EE, EE);

  // 1. LSTM front-end
  k_gates_init<<<(BB*FH)/256, 256, 0, stream>>>(b_ih, b_hh, gates);
  k_embed_gates<<<dim3(FH/64, (EE+HH)/64), 256, 0, stream>>>(ids, h, emb, W_ih, W_hh, gates);
  k_lstm<<<(BB*HH)/256, 256, 0, stream>>>(gates, c, ht_out, ct_out, hcatb);

  // 2. small precomputes
  k_q1p1<<<dim3(EE/256, BB), 256, 0, stream>>>(ht_out, ctx, aW1, ab1, kW1, kb1, q1, p1);
  k_p2<<<dim3(EE/256, KVN), 256, 0, stream>>>(kin, kW1, p2);

  // 3. key-attention path (fully fused; writes complete uklog rows)
  k_mfma_key<<<(BB*KVN)/32, 256, 0, stream>>>(p1, p2, kW2t, kb2, kW3, kb3, uklog);

  // 4. additive attention path
  k_mfma_a1<<<(BB*LL)/32, 256, 0, stream>>>(enc, aW1t, q1, U1);
  k_mfma_tanh_dot<<<(BB*LL)/32, 256, 0, stream>>>(U1, aW2t, ab2, aW3, ab3, ulog);
  k_hctx<<<dim3(HH/256, BB), 256, 0, stream>>>(ulog, enc, hcatb);

  // 5. output projection + log_softmax
  k_final_mfma<<<(VV + 63)/64, 256, 0, stream>>>(hcatb, alW, alb, uklog, y);
  k_lse_part<<<dim3(8, BB), 256, 0, stream>>>(y, pmax, psum);
  k_lse_apply<<<NBLK, 256, 0, stream>>>(y, pmax, psum);
}